// Round 7
// baseline (1626.683 us; speedup 1.0000x reference)
//
#include <hip/hip_runtime.h>
#include <math.h>

#define BS   256
#define NN   255
#define DIM  128
#define GAMMA 0.07
#define NUM_ITERS 1000

__device__ __forceinline__ double wred_d(double v) {
  #pragma unroll
  for (int k = 1; k < 64; k <<= 1) v += __shfl_xor(v, k, 64);
  return v;
}
__device__ __forceinline__ int wred_i(int v) {
  #pragma unroll
  for (int k = 1; k < 64; k <<= 1) v += __shfl_xor(v, k, 64);
  return v;
}

// lane-uniform float readlane (lane may be a uniform SGPR value)
__device__ __forceinline__ float RLF(float v, int lane) {
  return __int_as_float(__builtin_amdgcn_readlane(__float_as_int(v), lane));
}

// DPP wave64 sum -> total broadcast via readlane(63). VALU-only.
template <int CTRL, int RMASK>
__device__ __forceinline__ float dpp_add(float x) {
  int t = __builtin_amdgcn_update_dpp(0, __float_as_int(x), CTRL, RMASK, 0xf, true);
  return x + __int_as_float(t);
}
__device__ __forceinline__ float wred64_dpp(float x) {
  x = dpp_add<0x111, 0xf>(x);   // row_shr:1
  x = dpp_add<0x112, 0xf>(x);   // row_shr:2
  x = dpp_add<0x114, 0xf>(x);   // row_shr:4
  x = dpp_add<0x118, 0xf>(x);   // row_shr:8
  x = dpp_add<0x142, 0xa>(x);   // row_bcast:15
  x = dpp_add<0x143, 0xc>(x);   // row_bcast:31; lane63 = total
  return RLF(x, 63);
}

// ---------------- kernel 1: normalized features, stored transposed fp64 ----------------
__global__ void k_ftr(const float* __restrict__ z, double* __restrict__ ftrT) {
  int b = blockIdx.x;
  int d = threadIdx.x;
  double z0 = (double)z[b * 256 + d];
  double z1 = (double)z[b * 256 + 128 + d];
  double n = sqrt(z0 * z0 + z1 * z1);
  n = fmax(n, 1e-12);
  ftrT[d * 512 + b]       = z0 / n;
  ftrT[d * 512 + 256 + b] = z1 / n;
}

// ---------------- kernel 2: K = exp(-gamma * dist), fp64 math, fp32 store ----------------
__global__ void k_K(const double* __restrict__ ftrT, float* __restrict__ K,
                    double* __restrict__ pk_knt, double* __restrict__ pos_arr) {
  int i = blockIdx.x;
  int t = threadIdx.x;
  __shared__ double rowi[DIM];
  __shared__ double redd[4];
  if (t < DIM) rowi[t] = ftrT[t * 512 + i];
  __syncthreads();
  double xn = 0.0;
  #pragma unroll 8
  for (int d = 0; d < DIM; ++d) xn += rowi[d] * rowi[d];

  double knt_part = 0.0;
  #pragma unroll
  for (int h = 0; h < 2; ++h) {
    int j = t + h * 256;
    double dot = 0.0, sq = 0.0;
    #pragma unroll 8
    for (int d = 0; d < DIM; ++d) {
      double f = ftrT[d * 512 + j];
      dot += rowi[d] * f;
      sq  += f * f;
    }
    double dist = xn + sq - 2.0 * dot;
    double kv = exp(-GAMMA * dist);
    K[i * 512 + j] = (float)kv;
    if (h == 1) {
      if (j == 256 + i) pos_arr[i] = kv;
      else knt_part += kv;
    }
  }
  double w = wred_d(knt_part);
  if ((t & 63) == 0) redd[t >> 6] = w;
  __syncthreads();
  if (t == 0) pk_knt[i] = redd[0] + redd[1] + redd[2] + redd[3];
}

// ---------------- kernel 3: per-batch PGD, 8 waves, replicated state ----------------
// Wave (rb=rg&3, cb=rg>>2) owns rows [64rb,64rb+64) x cols {l+128cb, l+64+128cb}
// of KK in registers (128 floats/thread). Solver state is a-indexed (256 slots,
// dummy 0 at a==r) and REPLICATED in every wave, 4 contiguous cols per lane
// (a=4l..4l+3). Per iter:
//   region1: 64 readlane y-broadcasts (from own regs) + 128 fmac -> 2 part writes
//   B1
//   region2: every wave reads the 4 partials/col (1 b128/col) + gr, computes
//            g/norm(DPP)/update/y redundantly (bit-identical) in-register.
//   B2  (protects part[] reads from next iter's writes)
// No serial single-wave phase, no ytil round-trip (R5's ~1800 stall cyc/iter).
__global__ __launch_bounds__(512, 2) void k_pgd(
    const float* __restrict__ K, const float* __restrict__ alpha_init,
    double* __restrict__ neg_arr, double* __restrict__ sa_arr,
    int* __restrict__ cnt1, int* __restrict__ cntp, int* __restrict__ cnt0) {
  int r = blockIdx.x;
  int tid = threadIdx.x;
  int l = tid & 63;
  int rg = tid >> 6;
  int rb = rg & 3;          // row band (rows 64rb..64rb+64)
  int cb = rg >> 2;         // col half (cols 128cb..128cb+128)
  int ca = l + 128 * cb;    // this thread's matvec col 0
  int cbb = ca + 64;        // this thread's matvec col 1

  __shared__ __align__(16) float part[4][BS];   // 4 KB

  // register-resident KK block
  float kra[64], krb[64];
  #pragma unroll
  for (int i = 0; i < 64; ++i) {
    kra[i] = K[(64 * rb + i) * 512 + ca];
    krb[i] = K[(64 * rb + i) * 512 + cbb];
  }
  #pragma unroll
  for (int i = 0; i < 64; ++i)
    asm volatile("" : "+v"(kra[i]), "+v"(krb[i]));   // block rematerialization

  // replicated a-indexed state: lane l holds a = 4l..4l+3
  float al[4], ap[4], yv[4], kv[4], rm2[4];
  #pragma unroll
  for (int k = 0; k < 4; ++k) {
    int a = 4 * l + k;
    if (a == r) {
      al[k] = 0.f; ap[k] = 0.f; yv[k] = 0.f; kv[k] = 0.f; rm2[k] = 0.f;
    } else {
      int c = a - (a > r ? 1 : 0);
      float v = alpha_init[r * NN + c];
      v = fminf(fmaxf(v, 0.f), 1.f);
      al[k] = v; ap[k] = v; yv[k] = v;
      kv[k] = 1.0f - K[r * 512 + a];
      rm2[k] = 2.0f;
    }
  }
  float S = wred64_dpp((yv[0] + yv[1]) + (yv[2] + yv[3]));

  for (int it = 0; it < NUM_ITERS; ++it) {
    // ---- region 1: matvec partials (rows 64rb..64rb+64) ----
    // y-broadcast: ytil[64rb+i] lives at lane 16rb+(i>>2), comp i&3 (own wave)
    float acc0 = 0.f, acc1 = 0.f;
    int lbase = 16 * rb;
    #pragma unroll
    for (int i = 0; i < 64; ++i) {
      float ys = RLF(yv[i & 3], lbase + (i >> 2));
      acc0 = fmaf(kra[i], ys, acc0);
      acc1 = fmaf(krb[i], ys, acc1);
    }
    part[rb][ca]  = acc0;
    part[rb][cbb] = acc1;
    __syncthreads();                 // B1: all partials visible

    // ---- region 2: replicated update (every wave, bit-identical) ----
    float4 p0 = *(const float4*)&part[0][4 * l];
    float4 p1 = *(const float4*)&part[1][4 * l];
    float4 p2 = *(const float4*)&part[2][4 * l];
    float4 p3 = *(const float4*)&part[3][4 * l];
    float gr = (part[0][r] + part[1][r]) + (part[2][r] + part[3][r]);
    float gA[4];
    gA[0] = (p0.x + p1.x) + (p2.x + p3.x);
    gA[1] = (p0.y + p1.y) + (p2.y + p3.y);
    gA[2] = (p0.z + p1.z) + (p2.z + p3.z);
    gA[3] = (p0.w + p1.w) + (p2.w + p3.w);
    // a==r col: kv=rm2=0, yv=0, gA==gr (same add tree) -> g = 0 exactly
    float g[4];
    #pragma unroll
    for (int k = 0; k < 4; ++k)
      g[k] = (gA[k] - gr) - rm2[k] + kv[k] * S + 0.1f * yv[k];
    float n2 = wred64_dpp((g[0] * g[0] + g[1] * g[1]) + (g[2] * g[2] + g[3] * g[3]));
    float sinv = 0.001f / (sqrtf(n2) + 1e-12f);
    float beta = (float)(it + 1) / ((float)(it + 1) + 3.0f);
    float ysum = 0.f;
    #pragma unroll
    for (int k = 0; k < 4; ++k) {
      float na = fminf(fmaxf(fmaf(-sinv, g[k], yv[k]), 0.f), 1.f);
      ap[k] = al[k];
      al[k] = na;
      yv[k] = fmaf(beta, na - ap[k], na);
      ysum += yv[k];
    }
    S = wred64_dpp(ysum);
    __syncthreads();                 // B2: part reads done before next writes
  }

  // epilogue: every wave holds identical final state; wave 0 reduces+writes
  if (rg == 0) {
    double nl = 0.0, sa = 0.0;
    int c1 = 0, cp = 0, cz = 0;
    #pragma unroll
    for (int k = 0; k < 4; ++k) {
      int a = 4 * l + k;
      if (a != r) {
        float kx = K[a * 512 + 256 + r];     // KnT[r, c(a)]
        nl += (double)al[k] * (double)kx;
        sa += (double)al[k];
        c1 += (al[k] == 1.0f);
        cp += (al[k] > 0.0f);
        cz += (al[k] == 0.0f);
      }
    }
    nl = wred_d(nl); sa = wred_d(sa);
    c1 = wred_i(c1); cp = wred_i(cp); cz = wred_i(cz);
    if (l == 0) {
      neg_arr[r] = nl;
      sa_arr[r]  = sa;
      cnt1[r] = c1; cntp[r] = cp; cnt0[r] = cz;
    }
  }
}

// ---------------- kernel 4: final reduction to the 6 scalar outputs ----------------
__global__ void k_fin(const double* __restrict__ pk_knt, const double* __restrict__ pos_arr,
                      const double* __restrict__ neg_arr, const double* __restrict__ sa_arr,
                      const int* __restrict__ cnt1, const int* __restrict__ cntp,
                      const int* __restrict__ cnt0, float* __restrict__ out) {
  int t = threadIdx.x;  // 256
  __shared__ double rd[16];
  __shared__ int ri[12];
  double knt = pk_knt[t];
  double pos = pos_arr[t];
  double neg = neg_arr[t];
  double pl  = sa_arr[t] * pos_arr[t];
  int a1 = cnt1[t], ap = cntp[t], a0 = cnt0[t];
  knt = wred_d(knt); pos = wred_d(pos); neg = wred_d(neg); pl = wred_d(pl);
  a1 = wred_i(a1); ap = wred_i(ap); a0 = wred_i(a0);
  int w = t >> 6;
  if ((t & 63) == 0) {
    rd[w] = knt; rd[4 + w] = pos; rd[8 + w] = neg; rd[12 + w] = pl;
    ri[w] = a1; ri[4 + w] = ap; ri[8 + w] = a0;
  }
  __syncthreads();
  if (t == 0) {
    double kntS = rd[0] + rd[1] + rd[2] + rd[3];
    double posS = rd[4] + rd[5] + rd[6] + rd[7];
    double negS = rd[8] + rd[9] + rd[10] + rd[11];
    double plS  = rd[12] + rd[13] + rd[14] + rd[15];
    int c1t = ri[0] + ri[1] + ri[2] + ri[3];
    int cpt = ri[4] + ri[5] + ri[6] + ri[7];
    int c0t = ri[8] + ri[9] + ri[10] + ri[11];
    out[0] = (float)(negS / 256.0 - plS / 256.0);
    out[1] = (float)(posS / 256.0);
    out[2] = (float)(kntS / (256.0 * 255.0));
    out[3] = (float)c1t / ((float)cpt + 1e-10f);
    out[4] = (float)c0t / 65280.0f;
    out[5] = 0.0f;
  }
}

extern "C" void kernel_launch(void* const* d_in, const int* in_sizes, int n_in,
                              void* d_out, int out_size, void* d_ws, size_t ws_size,
                              hipStream_t stream) {
  const float* z     = (const float*)d_in[0];
  const float* ainit = (const float*)d_in[1];
  char* ws = (char*)d_ws;
  double* ftrT   = (double*)ws;                       // 512 KB
  float*  K      = (float*)(ws + 524288);             // 512 KB
  double* pk_knt = (double*)(ws + 1048576);
  double* pos_a  = (double*)(ws + 1048576 + 2048);
  double* neg_a  = (double*)(ws + 1048576 + 4096);
  double* sa_a   = (double*)(ws + 1048576 + 6144);
  int* cnt1 = (int*)(ws + 1048576 + 8192);
  int* cntp = (int*)(ws + 1048576 + 8192 + 1024);
  int* cnt0 = (int*)(ws + 1048576 + 8192 + 2048);
  float* out = (float*)d_out;

  k_ftr<<<256, 128, 0, stream>>>(z, ftrT);
  k_K  <<<256, 256, 0, stream>>>(ftrT, K, pk_knt, pos_a);
  k_pgd<<<256, 512, 0, stream>>>(K, ainit, neg_a, sa_a, cnt1, cntp, cnt0);
  k_fin<<<1, 256, 0, stream>>>(pk_knt, pos_a, neg_a, sa_a, cnt1, cntp, cnt0, out);
}

// Round 8
// 1541.905 us; speedup vs baseline: 1.0550x; 1.0550x over previous
//
#include <hip/hip_runtime.h>
#include <math.h>

#define BS   256
#define NN   255
#define DIM  128
#define GAMMA 0.07
#define NUM_ITERS 1000

__device__ __forceinline__ double wred_d(double v) {
  #pragma unroll
  for (int k = 1; k < 64; k <<= 1) v += __shfl_xor(v, k, 64);
  return v;
}
__device__ __forceinline__ int wred_i(int v) {
  #pragma unroll
  for (int k = 1; k < 64; k <<= 1) v += __shfl_xor(v, k, 64);
  return v;
}

// lane-uniform float readlane
__device__ __forceinline__ float RLF(float v, int lane) {
  return __int_as_float(__builtin_amdgcn_readlane(__float_as_int(v), lane));
}

// DPP wave64 sum -> total broadcast via readlane(63). VALU-only.
template <int CTRL, int RMASK>
__device__ __forceinline__ float dpp_add(float x) {
  int t = __builtin_amdgcn_update_dpp(0, __float_as_int(x), CTRL, RMASK, 0xf, true);
  return x + __int_as_float(t);
}
__device__ __forceinline__ float wred64_dpp(float x) {
  x = dpp_add<0x111, 0xf>(x);   // row_shr:1
  x = dpp_add<0x112, 0xf>(x);   // row_shr:2
  x = dpp_add<0x114, 0xf>(x);   // row_shr:4
  x = dpp_add<0x118, 0xf>(x);   // row_shr:8
  x = dpp_add<0x142, 0xa>(x);   // row_bcast:15
  x = dpp_add<0x143, 0xc>(x);   // row_bcast:31; lane63 = total
  return RLF(x, 63);
}

// ---------------- kernel 1: normalized features, stored transposed fp64 ----------------
__global__ void k_ftr(const float* __restrict__ z, double* __restrict__ ftrT) {
  int b = blockIdx.x;
  int d = threadIdx.x;
  double z0 = (double)z[b * 256 + d];
  double z1 = (double)z[b * 256 + 128 + d];
  double n = sqrt(z0 * z0 + z1 * z1);
  n = fmax(n, 1e-12);
  ftrT[d * 512 + b]       = z0 / n;
  ftrT[d * 512 + 256 + b] = z1 / n;
}

// ---------------- kernel 2: K = exp(-gamma * dist), fp64 math, fp32 store ----------------
__global__ void k_K(const double* __restrict__ ftrT, float* __restrict__ K,
                    double* __restrict__ pk_knt, double* __restrict__ pos_arr) {
  int i = blockIdx.x;
  int t = threadIdx.x;
  __shared__ double rowi[DIM];
  __shared__ double redd[4];
  if (t < DIM) rowi[t] = ftrT[t * 512 + i];
  __syncthreads();
  double xn = 0.0;
  #pragma unroll 8
  for (int d = 0; d < DIM; ++d) xn += rowi[d] * rowi[d];

  double knt_part = 0.0;
  #pragma unroll
  for (int h = 0; h < 2; ++h) {
    int j = t + h * 256;
    double dot = 0.0, sq = 0.0;
    #pragma unroll 8
    for (int d = 0; d < DIM; ++d) {
      double f = ftrT[d * 512 + j];
      dot += rowi[d] * f;
      sq  += f * f;
    }
    double dist = xn + sq - 2.0 * dot;
    double kv = exp(-GAMMA * dist);
    K[i * 512 + j] = (float)kv;
    if (h == 1) {
      if (j == 256 + i) pos_arr[i] = kv;
      else knt_part += kv;
    }
  }
  double w = wred_d(knt_part);
  if ((t & 63) == 0) redd[t >> 6] = w;
  __syncthreads();
  if (t == 0) pk_knt[i] = redd[0] + redd[1] + redd[2] + redd[3];
}

// ---------------- kernel 3: per-batch PGD, 16 waves ----------------
// Wave rg=(rb,cb): rb=rg&3 -> rows [64rb,64rb+64); cb=rg>>2 -> col 64cb+l.
// Each thread: 64 K floats (one column band), 1 fma per K element, y via
// LDS *broadcast* float4 (16 reads/wave replaces R7's 64 readlanes).
// Solver state (a-indexed incl. dummy 0 at a==r) replicated in every wave
// (R7 scheme, bit-identical across waves, absmax=0 verified); y-scatter is
// one conflict-free ds_write_b128 by wave 0. Two barriers/iter.
__global__ __launch_bounds__(1024, 4) void k_pgd(
    const float* __restrict__ K, const float* __restrict__ alpha_init,
    double* __restrict__ neg_arr, double* __restrict__ sa_arr,
    int* __restrict__ cnt1, int* __restrict__ cntp, int* __restrict__ cnt0) {
  int r = blockIdx.x;
  int tid = threadIdx.x;
  int l = tid & 63;
  int rg = tid >> 6;        // 0..15
  int rb = rg & 3;          // row band
  int cb = rg >> 2;         // col quarter
  int col = 64 * cb + l;    // this thread's matvec column

  __shared__ __align__(16) float ytil[BS];        // a-indexed, ytil[r]==0 always
  __shared__ __align__(16) float part[4][BS];     // [row band][a-col]

  // stage K column band: kcol[i] = K[(64rb+i)][col]; pin against remat
  float kcol[64];
  #pragma unroll
  for (int i = 0; i < 64; ++i)
    kcol[i] = K[(64 * rb + i) * 512 + col];
  #pragma unroll
  for (int i = 0; i < 64; ++i)
    asm volatile("" : "+v"(kcol[i]));

  // replicated a-indexed state: lane l holds a = 4l..4l+3
  float al[4], ap[4], yv[4], kv[4], rm2[4];
  #pragma unroll
  for (int k = 0; k < 4; ++k) {
    int a = 4 * l + k;
    if (a == r) {
      al[k] = 0.f; ap[k] = 0.f; yv[k] = 0.f; kv[k] = 0.f; rm2[k] = 0.f;
    } else {
      int c = a - (a > r ? 1 : 0);
      float v = alpha_init[r * NN + c];
      v = fminf(fmaxf(v, 0.f), 1.f);
      al[k] = v; ap[k] = v; yv[k] = v;
      kv[k] = 1.0f - K[r * 512 + a];
      rm2[k] = 2.0f;
    }
  }
  float S = wred64_dpp((yv[0] + yv[1]) + (yv[2] + yv[3]));
  if (rg == 0) {
    float4 y4 = {yv[0], yv[1], yv[2], yv[3]};
    *(float4*)&ytil[4 * l] = y4;     // a-indexed direct store (slot r holds 0)
  }
  __syncthreads();

  for (int it = 0; it < NUM_ITERS; ++it) {
    // ---- region 1: matvec partial for (row band rb, column col) ----
    const float4* yb = (const float4*)&ytil[64 * rb];
    float acc = 0.f;
    #pragma unroll
    for (int j = 0; j < 16; ++j) {
      float4 yq = yb[j];                       // wave-broadcast b128
      acc = fmaf(kcol[4 * j + 0], yq.x, acc);
      acc = fmaf(kcol[4 * j + 1], yq.y, acc);
      acc = fmaf(kcol[4 * j + 2], yq.z, acc);
      acc = fmaf(kcol[4 * j + 3], yq.w, acc);
    }
    part[rb][col] = acc;                       // conflict-free b32
    __syncthreads();                           // B1: partials visible

    // ---- region 2: replicated update (identical in all 16 waves) ----
    float4 p0 = *(const float4*)&part[0][4 * l];
    float4 p1 = *(const float4*)&part[1][4 * l];
    float4 p2 = *(const float4*)&part[2][4 * l];
    float4 p3 = *(const float4*)&part[3][4 * l];
    float gr = (part[0][r] + part[1][r]) + (part[2][r] + part[3][r]);
    float gA[4];
    gA[0] = (p0.x + p1.x) + (p2.x + p3.x);
    gA[1] = (p0.y + p1.y) + (p2.y + p3.y);
    gA[2] = (p0.z + p1.z) + (p2.z + p3.z);
    gA[3] = (p0.w + p1.w) + (p2.w + p3.w);
    // a==r col: kv=rm2=0, yv=0, gA==gr (same add tree) -> g = 0 exactly
    float g[4];
    #pragma unroll
    for (int k = 0; k < 4; ++k)
      g[k] = (gA[k] - gr) - rm2[k] + kv[k] * S + 0.1f * yv[k];
    float n2 = wred64_dpp((g[0] * g[0] + g[1] * g[1]) + (g[2] * g[2] + g[3] * g[3]));
    float sinv = 0.001f / (sqrtf(n2) + 1e-12f);
    float beta = (float)(it + 1) / ((float)(it + 1) + 3.0f);
    float ysum = 0.f;
    #pragma unroll
    for (int k = 0; k < 4; ++k) {
      float na = fminf(fmaxf(fmaf(-sinv, g[k], yv[k]), 0.f), 1.f);
      ap[k] = al[k];
      al[k] = na;
      yv[k] = fmaf(beta, na - ap[k], na);
      ysum += yv[k];
    }
    S = wred64_dpp(ysum);
    if (rg == 0) {
      float4 y4 = {yv[0], yv[1], yv[2], yv[3]};
      *(float4*)&ytil[4 * l] = y4;             // one b128, conflict-free
    }
    __syncthreads();                           // B2: ytil ready, part reads done
  }

  // epilogue: every wave holds identical final state; wave 0 reduces+writes
  if (rg == 0) {
    double nl = 0.0, sa = 0.0;
    int c1 = 0, cp = 0, cz = 0;
    #pragma unroll
    for (int k = 0; k < 4; ++k) {
      int a = 4 * l + k;
      if (a != r) {
        float kx = K[a * 512 + 256 + r];     // KnT[r, c(a)]
        nl += (double)al[k] * (double)kx;
        sa += (double)al[k];
        c1 += (al[k] == 1.0f);
        cp += (al[k] > 0.0f);
        cz += (al[k] == 0.0f);
      }
    }
    nl = wred_d(nl); sa = wred_d(sa);
    c1 = wred_i(c1); cp = wred_i(cp); cz = wred_i(cz);
    if (l == 0) {
      neg_arr[r] = nl;
      sa_arr[r]  = sa;
      cnt1[r] = c1; cntp[r] = cp; cnt0[r] = cz;
    }
  }
}

// ---------------- kernel 4: final reduction to the 6 scalar outputs ----------------
__global__ void k_fin(const double* __restrict__ pk_knt, const double* __restrict__ pos_arr,
                      const double* __restrict__ neg_arr, const double* __restrict__ sa_arr,
                      const int* __restrict__ cnt1, const int* __restrict__ cntp,
                      const int* __restrict__ cnt0, float* __restrict__ out) {
  int t = threadIdx.x;  // 256
  __shared__ double rd[16];
  __shared__ int ri[12];
  double knt = pk_knt[t];
  double pos = pos_arr[t];
  double neg = neg_arr[t];
  double pl  = sa_arr[t] * pos_arr[t];
  int a1 = cnt1[t], ap = cntp[t], a0 = cnt0[t];
  knt = wred_d(knt); pos = wred_d(pos); neg = wred_d(neg); pl = wred_d(pl);
  a1 = wred_i(a1); ap = wred_i(ap); a0 = wred_i(a0);
  int w = t >> 6;
  if ((t & 63) == 0) {
    rd[w] = knt; rd[4 + w] = pos; rd[8 + w] = neg; rd[12 + w] = pl;
    ri[w] = a1; ri[4 + w] = ap; ri[8 + w] = a0;
  }
  __syncthreads();
  if (t == 0) {
    double kntS = rd[0] + rd[1] + rd[2] + rd[3];
    double posS = rd[4] + rd[5] + rd[6] + rd[7];
    double negS = rd[8] + rd[9] + rd[10] + rd[11];
    double plS  = rd[12] + rd[13] + rd[14] + rd[15];
    int c1t = ri[0] + ri[1] + ri[2] + ri[3];
    int cpt = ri[4] + ri[5] + ri[6] + ri[7];
    int c0t = ri[8] + ri[9] + ri[10] + ri[11];
    out[0] = (float)(negS / 256.0 - plS / 256.0);
    out[1] = (float)(posS / 256.0);
    out[2] = (float)(kntS / (256.0 * 255.0));
    out[3] = (float)c1t / ((float)cpt + 1e-10f);
    out[4] = (float)c0t / 65280.0f;
    out[5] = 0.0f;
  }
}

extern "C" void kernel_launch(void* const* d_in, const int* in_sizes, int n_in,
                              void* d_out, int out_size, void* d_ws, size_t ws_size,
                              hipStream_t stream) {
  const float* z     = (const float*)d_in[0];
  const float* ainit = (const float*)d_in[1];
  char* ws = (char*)d_ws;
  double* ftrT   = (double*)ws;                       // 512 KB
  float*  K      = (float*)(ws + 524288);             // 512 KB
  double* pk_knt = (double*)(ws + 1048576);
  double* pos_a  = (double*)(ws + 1048576 + 2048);
  double* neg_a  = (double*)(ws + 1048576 + 4096);
  double* sa_a   = (double*)(ws + 1048576 + 6144);
  int* cnt1 = (int*)(ws + 1048576 + 8192);
  int* cntp = (int*)(ws + 1048576 + 8192 + 1024);
  int* cnt0 = (int*)(ws + 1048576 + 8192 + 2048);
  float* out = (float*)d_out;

  k_ftr<<<256, 128, 0, stream>>>(z, ftrT);
  k_K  <<<256, 256, 0, stream>>>(ftrT, K, pk_knt, pos_a);
  k_pgd<<<256, 1024, 0, stream>>>(K, ainit, neg_a, sa_a, cnt1, cntp, cnt0);
  k_fin<<<1, 256, 0, stream>>>(pk_knt, pos_a, neg_a, sa_a, cnt1, cntp, cnt0, out);
}

// Round 9
// 998.814 us; speedup vs baseline: 1.6286x; 1.5437x over previous
//
#include <hip/hip_runtime.h>
#include <math.h>

#define BS   256
#define NN   255
#define DIM  128
#define GAMMA 0.07
#define NUM_ITERS 1000

typedef float v2f __attribute__((ext_vector_type(2)));

__device__ __forceinline__ double wred_d(double v) {
  #pragma unroll
  for (int k = 1; k < 64; k <<= 1) v += __shfl_xor(v, k, 64);
  return v;
}
__device__ __forceinline__ int wred_i(int v) {
  #pragma unroll
  for (int k = 1; k < 64; k <<= 1) v += __shfl_xor(v, k, 64);
  return v;
}

// lane-uniform float readlane
__device__ __forceinline__ float RLF(float v, int lane) {
  return __int_as_float(__builtin_amdgcn_readlane(__float_as_int(v), lane));
}

// DPP wave64 sum -> total broadcast via readlane(63). VALU-only.
template <int CTRL, int RMASK>
__device__ __forceinline__ float dpp_add(float x) {
  int t = __builtin_amdgcn_update_dpp(0, __float_as_int(x), CTRL, RMASK, 0xf, true);
  return x + __int_as_float(t);
}
__device__ __forceinline__ float wred64_dpp(float x) {
  x = dpp_add<0x111, 0xf>(x);   // row_shr:1
  x = dpp_add<0x112, 0xf>(x);   // row_shr:2
  x = dpp_add<0x114, 0xf>(x);   // row_shr:4
  x = dpp_add<0x118, 0xf>(x);   // row_shr:8
  x = dpp_add<0x142, 0xa>(x);   // row_bcast:15
  x = dpp_add<0x143, 0xc>(x);   // row_bcast:31; lane63 = total
  return RLF(x, 63);
}

// packed dual-fp32 FMA: acc.lo += k.lo*y.lo; acc.hi += k.hi*y.hi (VOP3P).
// "v" pair constraints force true VGPR residency for kcol (R5-R8: compiler
// kept K in AGPRs; VGPR_Count 56-64 was the tell).
__device__ __forceinline__ void pk_fma(v2f& acc, const v2f& k, const v2f& y) {
  asm("v_pk_fma_f32 %0, %1, %2, %0" : "+v"(acc) : "v"(k), "v"(y));
}

// ---------------- kernel 1: normalized features, stored transposed fp64 ----------------
__global__ void k_ftr(const float* __restrict__ z, double* __restrict__ ftrT) {
  int b = blockIdx.x;
  int d = threadIdx.x;
  double z0 = (double)z[b * 256 + d];
  double z1 = (double)z[b * 256 + 128 + d];
  double n = sqrt(z0 * z0 + z1 * z1);
  n = fmax(n, 1e-12);
  ftrT[d * 512 + b]       = z0 / n;
  ftrT[d * 512 + 256 + b] = z1 / n;
}

// ---------------- kernel 2: K = exp(-gamma * dist), fp64 math, fp32 store ----------------
__global__ void k_K(const double* __restrict__ ftrT, float* __restrict__ K,
                    double* __restrict__ pk_knt, double* __restrict__ pos_arr) {
  int i = blockIdx.x;
  int t = threadIdx.x;
  __shared__ double rowi[DIM];
  __shared__ double redd[4];
  if (t < DIM) rowi[t] = ftrT[t * 512 + i];
  __syncthreads();
  double xn = 0.0;
  #pragma unroll 8
  for (int d = 0; d < DIM; ++d) xn += rowi[d] * rowi[d];

  double knt_part = 0.0;
  #pragma unroll
  for (int h = 0; h < 2; ++h) {
    int j = t + h * 256;
    double dot = 0.0, sq = 0.0;
    #pragma unroll 8
    for (int d = 0; d < DIM; ++d) {
      double f = ftrT[d * 512 + j];
      dot += rowi[d] * f;
      sq  += f * f;
    }
    double dist = xn + sq - 2.0 * dot;
    double kv = exp(-GAMMA * dist);
    K[i * 512 + j] = (float)kv;
    if (h == 1) {
      if (j == 256 + i) pos_arr[i] = kv;
      else knt_part += kv;
    }
  }
  double w = wred_d(knt_part);
  if ((t & 63) == 0) redd[t >> 6] = w;
  __syncthreads();
  if (t == 0) pk_knt[i] = redd[0] + redd[1] + redd[2] + redd[3];
}

// ---------------- kernel 3: per-batch PGD, 16 waves, pk_fma matvec ----------------
// Wave rg=(rb,cb): rb=rg&3 -> rows [64rb,64rb+64); cb=rg>>2 -> col 64cb+l.
// Thread holds its 64-row K column band as 32 VGPR pairs; matvec = 16
// broadcast ds_read_b128 + 32 v_pk_fma_f32. Solver state lives ONLY in wave 0
// (region2 de-replicated: wall time is set by the serial chain anyway, and
// R8 showed 16-way replication costs ~830 issue-cyc/SIMD/iter). 2 barriers.
__global__ __launch_bounds__(1024, 4) void k_pgd(
    const float* __restrict__ K, const float* __restrict__ alpha_init,
    double* __restrict__ neg_arr, double* __restrict__ sa_arr,
    int* __restrict__ cnt1, int* __restrict__ cntp, int* __restrict__ cnt0) {
  int r = blockIdx.x;
  int tid = threadIdx.x;
  int l = tid & 63;
  int rg = tid >> 6;        // 0..15
  int rb = rg & 3;          // row band
  int cb = rg >> 2;         // col quarter
  int col = 64 * cb + l;    // this thread's matvec column

  __shared__ __align__(16) float ytil[BS];        // a-indexed, ytil[r]==0 always
  __shared__ __align__(16) float part[4][BS];     // [row band][a-col]

  // stage K column band as row-pairs: kp[j] = (K[64rb+2j][col], K[64rb+2j+1][col])
  v2f kp[32];
  #pragma unroll
  for (int j = 0; j < 32; ++j) {
    kp[j].x = K[(64 * rb + 2 * j + 0) * 512 + col];
    kp[j].y = K[(64 * rb + 2 * j + 1) * 512 + col];
  }
  #pragma unroll
  for (int j = 0; j < 32; ++j)
    asm volatile("" : "+v"(kp[j]));   // pin VGPR pairs; block rematerialization

  // wave-0-only solver state: lane l holds a = 4l..4l+3 (a-indexed, dummy at a==r)
  float al[4], ap[4], yv[4], kv[4], rm2[4];
  if (rg == 0) {
    #pragma unroll
    for (int k = 0; k < 4; ++k) {
      int a = 4 * l + k;
      if (a == r) {
        al[k] = 0.f; ap[k] = 0.f; yv[k] = 0.f; kv[k] = 0.f; rm2[k] = 0.f;
      } else {
        int c = a - (a > r ? 1 : 0);
        float v = alpha_init[r * NN + c];
        v = fminf(fmaxf(v, 0.f), 1.f);
        al[k] = v; ap[k] = v; yv[k] = v;
        kv[k] = 1.0f - K[r * 512 + a];
        rm2[k] = 2.0f;
      }
    }
    float4 y4 = {yv[0], yv[1], yv[2], yv[3]};
    *(float4*)&ytil[4 * l] = y4;     // a-indexed direct store (slot r holds 0)
  }
  float S = 0.f;
  if (rg == 0) S = wred64_dpp((yv[0] + yv[1]) + (yv[2] + yv[3]));
  __syncthreads();

  for (int it = 0; it < NUM_ITERS; ++it) {
    // ---- region 1: matvec partial for (row band rb, column col) ----
    const float4* yb = (const float4*)&ytil[64 * rb];
    v2f acc = {0.f, 0.f};
    #pragma unroll
    for (int jq = 0; jq < 16; ++jq) {
      float4 yq = yb[jq];                      // wave-broadcast b128
      v2f ylo = {yq.x, yq.y};
      v2f yhi = {yq.z, yq.w};
      pk_fma(acc, kp[2 * jq + 0], ylo);
      pk_fma(acc, kp[2 * jq + 1], yhi);
    }
    part[rb][col] = acc.x + acc.y;             // conflict-free b32
    __syncthreads();                           // B1: partials visible

    // ---- region 2: update on wave 0 only ----
    if (rg == 0) {
      float4 p0 = *(const float4*)&part[0][4 * l];
      float4 p1 = *(const float4*)&part[1][4 * l];
      float4 p2 = *(const float4*)&part[2][4 * l];
      float4 p3 = *(const float4*)&part[3][4 * l];
      float gr = (part[0][r] + part[1][r]) + (part[2][r] + part[3][r]);
      float gA[4];
      gA[0] = (p0.x + p1.x) + (p2.x + p3.x);
      gA[1] = (p0.y + p1.y) + (p2.y + p3.y);
      gA[2] = (p0.z + p1.z) + (p2.z + p3.z);
      gA[3] = (p0.w + p1.w) + (p2.w + p3.w);
      // a==r col: kv=rm2=yv=0 and gA==gr (same add tree) -> g = 0 exactly
      float g[4];
      #pragma unroll
      for (int k = 0; k < 4; ++k)
        g[k] = (gA[k] - gr) - rm2[k] + kv[k] * S + 0.1f * yv[k];
      float n2 = wred64_dpp((g[0] * g[0] + g[1] * g[1]) + (g[2] * g[2] + g[3] * g[3]));
      float sinv = 0.001f / (sqrtf(n2) + 1e-12f);
      float beta = (float)(it + 1) / ((float)(it + 1) + 3.0f);
      float ysum = 0.f;
      #pragma unroll
      for (int k = 0; k < 4; ++k) {
        float na = fminf(fmaxf(fmaf(-sinv, g[k], yv[k]), 0.f), 1.f);
        ap[k] = al[k];
        al[k] = na;
        yv[k] = fmaf(beta, na - ap[k], na);
        ysum += yv[k];
      }
      S = wred64_dpp(ysum);
      float4 y4 = {yv[0], yv[1], yv[2], yv[3]};
      *(float4*)&ytil[4 * l] = y4;             // one b128, conflict-free
    }
    __syncthreads();                           // B2: ytil ready, part reads done
  }

  // epilogue: wave 0 holds the state — single-wave fp64 reductions
  if (rg == 0) {
    double nl = 0.0, sa = 0.0;
    int c1 = 0, cp = 0, cz = 0;
    #pragma unroll
    for (int k = 0; k < 4; ++k) {
      int a = 4 * l + k;
      if (a != r) {
        float kx = K[a * 512 + 256 + r];     // KnT[r, c(a)]
        nl += (double)al[k] * (double)kx;
        sa += (double)al[k];
        c1 += (al[k] == 1.0f);
        cp += (al[k] > 0.0f);
        cz += (al[k] == 0.0f);
      }
    }
    nl = wred_d(nl); sa = wred_d(sa);
    c1 = wred_i(c1); cp = wred_i(cp); cz = wred_i(cz);
    if (l == 0) {
      neg_arr[r] = nl;
      sa_arr[r]  = sa;
      cnt1[r] = c1; cntp[r] = cp; cnt0[r] = cz;
    }
  }
}

// ---------------- kernel 4: final reduction to the 6 scalar outputs ----------------
__global__ void k_fin(const double* __restrict__ pk_knt, const double* __restrict__ pos_arr,
                      const double* __restrict__ neg_arr, const double* __restrict__ sa_arr,
                      const int* __restrict__ cnt1, const int* __restrict__ cntp,
                      const int* __restrict__ cnt0, float* __restrict__ out) {
  int t = threadIdx.x;  // 256
  __shared__ double rd[16];
  __shared__ int ri[12];
  double knt = pk_knt[t];
  double pos = pos_arr[t];
  double neg = neg_arr[t];
  double pl  = sa_arr[t] * pos_arr[t];
  int a1 = cnt1[t], ap = cntp[t], a0 = cnt0[t];
  knt = wred_d(knt); pos = wred_d(pos); neg = wred_d(neg); pl = wred_d(pl);
  a1 = wred_i(a1); ap = wred_i(ap); a0 = wred_i(a0);
  int w = t >> 6;
  if ((t & 63) == 0) {
    rd[w] = knt; rd[4 + w] = pos; rd[8 + w] = neg; rd[12 + w] = pl;
    ri[w] = a1; ri[4 + w] = ap; ri[8 + w] = a0;
  }
  __syncthreads();
  if (t == 0) {
    double kntS = rd[0] + rd[1] + rd[2] + rd[3];
    double posS = rd[4] + rd[5] + rd[6] + rd[7];
    double negS = rd[8] + rd[9] + rd[10] + rd[11];
    double plS  = rd[12] + rd[13] + rd[14] + rd[15];
    int c1t = ri[0] + ri[1] + ri[2] + ri[3];
    int cpt = ri[4] + ri[5] + ri[6] + ri[7];
    int c0t = ri[8] + ri[9] + ri[10] + ri[11];
    out[0] = (float)(negS / 256.0 - plS / 256.0);
    out[1] = (float)(posS / 256.0);
    out[2] = (float)(kntS / (256.0 * 255.0));
    out[3] = (float)c1t / ((float)cpt + 1e-10f);
    out[4] = (float)c0t / 65280.0f;
    out[5] = 0.0f;
  }
}

extern "C" void kernel_launch(void* const* d_in, const int* in_sizes, int n_in,
                              void* d_out, int out_size, void* d_ws, size_t ws_size,
                              hipStream_t stream) {
  const float* z     = (const float*)d_in[0];
  const float* ainit = (const float*)d_in[1];
  char* ws = (char*)d_ws;
  double* ftrT   = (double*)ws;                       // 512 KB
  float*  K      = (float*)(ws + 524288);             // 512 KB
  double* pk_knt = (double*)(ws + 1048576);
  double* pos_a  = (double*)(ws + 1048576 + 2048);
  double* neg_a  = (double*)(ws + 1048576 + 4096);
  double* sa_a   = (double*)(ws + 1048576 + 6144);
  int* cnt1 = (int*)(ws + 1048576 + 8192);
  int* cntp = (int*)(ws + 1048576 + 8192 + 1024);
  int* cnt0 = (int*)(ws + 1048576 + 8192 + 2048);
  float* out = (float*)d_out;

  k_ftr<<<256, 128, 0, stream>>>(z, ftrT);
  k_K  <<<256, 256, 0, stream>>>(ftrT, K, pk_knt, pos_a);
  k_pgd<<<256, 1024, 0, stream>>>(K, ainit, neg_a, sa_a, cnt1, cntp, cnt0);
  k_fin<<<1, 256, 0, stream>>>(pk_knt, pos_a, neg_a, sa_a, cnt1, cntp, cnt0, out);
}